// Round 1
// baseline (1220.589 us; speedup 1.0000x reference)
//
#include <hip/hip_runtime.h>

#define SEQ  2048
#define EMB  256
#define NH   8
#define HD   32
#define NB   4
#define KTOP 204

typedef unsigned long long ull;

__device__ __forceinline__ unsigned f2ord(float f) {
  unsigned u = __float_as_uint(f);
  return (u & 0x80000000u) ? ~u : (u | 0x80000000u);
}

// ---------------------------------------------------------------------------
// Generic fp32 GEMM: C[m,n] = scale * sum_k A[m,k]*B[n,k] + bias[n]
// 64x64 C tile per 256-thread block, 4x4 per thread, K=EMB=256 fixed.
// ---------------------------------------------------------------------------
__global__ __launch_bounds__(256) void gemm_abT(
    const float* __restrict__ A, const float* __restrict__ B,
    const float* __restrict__ bias, float* __restrict__ C,
    int lda, int ldb, int ldc,
    long bsA, long bsB, long bsC, float scale)
{
  __shared__ float As[16][68];
  __shared__ float Bs[16][68];
  const int tid = threadIdx.x;
  const int m0 = blockIdx.x * 64, n0 = blockIdx.y * 64;
  const float* Ab = A + (size_t)blockIdx.z * bsA;
  const float* Bb = B + (size_t)blockIdx.z * bsB;
  float* Cb = C + (size_t)blockIdx.z * bsC;
  const int lm = tid >> 2;          // 0..63
  const int lk = (tid & 3) << 2;    // 0,4,8,12
  const int mt = tid >> 4;          // 0..15
  const int nt = tid & 15;          // 0..15
  float acc[4][4] = {{0.f}};
  for (int k0 = 0; k0 < EMB; k0 += 16) {
    float4 av = *(const float4*)(Ab + (size_t)(m0 + lm) * lda + k0 + lk);
    float4 bv = *(const float4*)(Bb + (size_t)(n0 + lm) * ldb + k0 + lk);
    __syncthreads();
    As[lk+0][lm] = av.x; As[lk+1][lm] = av.y; As[lk+2][lm] = av.z; As[lk+3][lm] = av.w;
    Bs[lk+0][lm] = bv.x; Bs[lk+1][lm] = bv.y; Bs[lk+2][lm] = bv.z; Bs[lk+3][lm] = bv.w;
    __syncthreads();
#pragma unroll
    for (int kk = 0; kk < 16; ++kk) {
      float4 a4 = *(const float4*)&As[kk][mt << 2];
      float4 b4 = *(const float4*)&Bs[kk][nt << 2];
      acc[0][0] += a4.x*b4.x; acc[0][1] += a4.x*b4.y; acc[0][2] += a4.x*b4.z; acc[0][3] += a4.x*b4.w;
      acc[1][0] += a4.y*b4.x; acc[1][1] += a4.y*b4.y; acc[1][2] += a4.y*b4.z; acc[1][3] += a4.y*b4.w;
      acc[2][0] += a4.z*b4.x; acc[2][1] += a4.z*b4.y; acc[2][2] += a4.z*b4.z; acc[2][3] += a4.z*b4.w;
      acc[3][0] += a4.w*b4.x; acc[3][1] += a4.w*b4.y; acc[3][2] += a4.w*b4.z; acc[3][3] += a4.w*b4.w;
    }
  }
  float4 bi = make_float4(0.f, 0.f, 0.f, 0.f);
  if (bias) bi = *(const float4*)(bias + n0 + (nt << 2));
#pragma unroll
  for (int r = 0; r < 4; ++r) {
    float4 o;
    o.x = acc[r][0]*scale + bi.x;
    o.y = acc[r][1]*scale + bi.y;
    o.z = acc[r][2]*scale + bi.z;
    o.w = acc[r][3]*scale + bi.w;
    *(float4*)(Cb + (size_t)(m0 + (mt << 2) + r) * ldc + n0 + (nt << 2)) = o;
  }
}

// ---------------------------------------------------------------------------
// Top-k=204 per row of scores [8192 rows x 2048]. One block per row.
// Binary search k-th largest on ordinal-mapped bits; ties resolved in
// ascending index order (matches lax.top_k / stable argsort semantics).
// Emits 32 x u64 mask words per row.
// ---------------------------------------------------------------------------
__global__ __launch_bounds__(256) void topk_mask(
    const float* __restrict__ scores, ull* __restrict__ maskw)
{
  const int r = blockIdx.x;
  const int tid = threadIdx.x;
  const float* row = scores + (size_t)r * SEQ;
  unsigned key[8];
  {
    float4 f0 = *(const float4*)(row + tid * 8);
    float4 f1 = *(const float4*)(row + tid * 8 + 4);
    key[0]=f2ord(f0.x); key[1]=f2ord(f0.y); key[2]=f2ord(f0.z); key[3]=f2ord(f0.w);
    key[4]=f2ord(f1.x); key[5]=f2ord(f1.y); key[6]=f2ord(f1.z); key[7]=f2ord(f1.w);
  }
  __shared__ int wsum[4];
  __shared__ int total_sh;
  __shared__ int scan_sh[256];
  __shared__ unsigned char bytesh[256];
  const int lane = tid & 63, wid = tid >> 6;

  unsigned lo = 0u, hi = 0xFFFFFFFFu;
  while (lo < hi) {
    unsigned mid = (unsigned)((((ull)lo + (ull)hi) + 1ull) >> 1);
    int c = 0;
#pragma unroll
    for (int j = 0; j < 8; ++j) c += (key[j] >= mid) ? 1 : 0;
    for (int off = 32; off > 0; off >>= 1) c += __shfl_down(c, off, 64);
    if (lane == 0) wsum[wid] = c;
    __syncthreads();
    if (tid == 0) total_sh = wsum[0] + wsum[1] + wsum[2] + wsum[3];
    __syncthreads();
    int cnt = total_sh;
    __syncthreads();
    if (cnt >= KTOP) lo = mid; else hi = mid - 1;
  }
  const unsigned V = lo;

  int cgt = 0, ceq = 0;
#pragma unroll
  for (int j = 0; j < 8; ++j) {
    cgt += (key[j] > V) ? 1 : 0;
    ceq += (key[j] == V) ? 1 : 0;
  }
  int cg = cgt;
  for (int off = 32; off > 0; off >>= 1) cg += __shfl_down(cg, off, 64);
  if (lane == 0) wsum[wid] = cg;
  __syncthreads();
  if (tid == 0) total_sh = wsum[0] + wsum[1] + wsum[2] + wsum[3];
  __syncthreads();
  const int MEQ = KTOP - total_sh;   // >=1 equals to take, lowest index first

  scan_sh[tid] = ceq;
  __syncthreads();
  for (int off = 1; off < 256; off <<= 1) {
    int v = (tid >= off) ? scan_sh[tid - off] : 0;
    __syncthreads();
    scan_sh[tid] += v;
    __syncthreads();
  }
  int run = scan_sh[tid] - ceq;      // equals strictly before my chunk

  unsigned bits = 0;
#pragma unroll
  for (int j = 0; j < 8; ++j) {
    bool e = (key[j] == V);
    bool sel = (key[j] > V) || (e && (run < MEQ));
    if (e) run++;
    if (sel) bits |= (1u << j);
  }
  bytesh[tid] = (unsigned char)bits;
  __syncthreads();
  if (tid < 32) {
    ull w = 0;
#pragma unroll
    for (int j = 0; j < 8; ++j)
      w |= (ull)bytesh[tid * 8 + j] << (8 * j);
    maskw[(size_t)r * 32 + tid] = w;
  }
}

__global__ __launch_bounds__(256) void zero_attn(float4* __restrict__ p, int n4)
{
  int i = blockIdx.x * 256 + threadIdx.x;
  if (i < n4) p[i] = make_float4(0.f, 0.f, 0.f, 0.f);
}

// ---------------------------------------------------------------------------
// Pass A: softmax denominator per (b,h,q). Block = (qtile=32, h, b).
// Thread (q,tg): q = tid>>3, tg = tid&7; q-row of head h in 32 regs.
// No max-subtraction: logits bounded (|l| <~ 8), exp safe in fp32.
// ---------------------------------------------------------------------------
__global__ __launch_bounds__(256) void attn_den(
    const float* __restrict__ qb, const float* __restrict__ kb,
    const ull* __restrict__ maskw, float* __restrict__ den)
{
  const int qt = blockIdx.x, h = blockIdx.y, b = blockIdx.z;
  const int q0 = qt * 32;
  const int tid = threadIdx.x;
  const int q = tid >> 3, tg = tid & 7;
  __shared__ float ksh[64 * 40];     // [t][d] pad 40 -> conflict-free strided t
  __shared__ ull msh[32 * 32];       // [q][word]
  __shared__ float red[32 * 8];

  for (int j = tid; j < 1024; j += 256)
    msh[j] = maskw[((size_t)(b * SEQ + q0 + (j >> 5))) * 32 + (j & 31)];

  const float* qrow = qb + ((size_t)(b * SEQ + q0 + q)) * EMB + h * HD;
  float4 qv[8];
#pragma unroll
  for (int j = 0; j < 8; ++j) qv[j] = *(const float4*)(qrow + 4 * j);

  const float scale = 0.17677669529663687f;  // 1/sqrt(32)
  float dacc = 0.f;

  for (int t0 = 0; t0 < SEQ; t0 += 64) {
    __syncthreads();
#pragma unroll
    for (int j = 0; j < 2; ++j) {
      int jj = tid + j * 256;
      int t = jj >> 3, c = (jj & 7) << 2;
      float4 kv = *(const float4*)(kb + ((size_t)(b * SEQ + t0 + t)) * EMB + h * HD + c);
      *(float4*)&ksh[t * 40 + c] = kv;
    }
    __syncthreads();
    ull mw = msh[q * 32 + (t0 >> 6)];
#pragma unroll
    for (int i = 0; i < 8; ++i) {
      int t = tg + 8 * i;
      if ((mw >> t) & 1ull) {
        const float* kr = &ksh[t * 40];
        float s = 0.f;
#pragma unroll
        for (int j = 0; j < 8; ++j) {
          float4 kv = *(const float4*)(kr + 4 * j);
          s += qv[j].x*kv.x + qv[j].y*kv.y + qv[j].z*kv.z + qv[j].w*kv.w;
        }
        dacc += __expf(s * scale);
      }
    }
  }
  red[q * 8 + tg] = dacc;
  __syncthreads();
  if (tid < 32) {
    float s = 0.f;
#pragma unroll
    for (int j = 0; j < 8; ++j) s += red[tid * 8 + j];
    den[((size_t)(b * NH + h)) * SEQ + q0 + tid] = s;
  }
}

// ---------------------------------------------------------------------------
// Pass B: probs = exp(l)/den; attn_weights += probs/8 (atomic, sparse ~10%);
// ctx accumulation with cross-tg LDS reduction.
// ---------------------------------------------------------------------------
__global__ __launch_bounds__(256) void attn_ctx(
    const float* __restrict__ qb, const float* __restrict__ kb,
    const float* __restrict__ vb, const ull* __restrict__ maskw,
    const float* __restrict__ den, float* __restrict__ attn,
    float* __restrict__ ctxb)
{
  const int qt = blockIdx.x, h = blockIdx.y, b = blockIdx.z;
  const int q0 = qt * 32;
  const int tid = threadIdx.x;
  const int q = tid >> 3, tg = tid & 7;
  __shared__ float ksh[64 * 40];
  __shared__ float vsh[64 * 40];
  __shared__ ull msh[32 * 32];
  __shared__ float csh[8 * 32 * 33];  // [tg][q][e] pad 33

  for (int j = tid; j < 1024; j += 256)
    msh[j] = maskw[((size_t)(b * SEQ + q0 + (j >> 5))) * 32 + (j & 31)];

  const float* qrow = qb + ((size_t)(b * SEQ + q0 + q)) * EMB + h * HD;
  float4 qv[8];
#pragma unroll
  for (int j = 0; j < 8; ++j) qv[j] = *(const float4*)(qrow + 4 * j);

  const float idv = 1.f / den[((size_t)(b * NH + h)) * SEQ + q0 + q];
  const float scale = 0.17677669529663687f;
  float ctxa[32];
#pragma unroll
  for (int e = 0; e < 32; ++e) ctxa[e] = 0.f;

  for (int t0 = 0; t0 < SEQ; t0 += 64) {
    __syncthreads();
#pragma unroll
    for (int j = 0; j < 2; ++j) {
      int jj = tid + j * 256;
      int t = jj >> 3, c = (jj & 7) << 2;
      size_t gidx = ((size_t)(b * SEQ + t0 + t)) * EMB + h * HD + c;
      *(float4*)&ksh[t * 40 + c] = *(const float4*)(kb + gidx);
      *(float4*)&vsh[t * 40 + c] = *(const float4*)(vb + gidx);
    }
    __syncthreads();
    ull mw = msh[q * 32 + (t0 >> 6)];
#pragma unroll
    for (int i = 0; i < 8; ++i) {
      int t = tg + 8 * i;
      if ((mw >> t) & 1ull) {
        const float* kr = &ksh[t * 40];
        float s = 0.f;
#pragma unroll
        for (int j = 0; j < 8; ++j) {
          float4 kv = *(const float4*)(kr + 4 * j);
          s += qv[j].x*kv.x + qv[j].y*kv.y + qv[j].z*kv.z + qv[j].w*kv.w;
        }
        float p = __expf(s * scale) * idv;
        atomicAdd(attn + ((size_t)(b * SEQ + q0 + q)) * SEQ + t0 + t, p * 0.125f);
        const float* vr = &vsh[t * 40];
#pragma unroll
        for (int j = 0; j < 8; ++j) {
          float4 vv = *(const float4*)(vr + 4 * j);
          ctxa[4*j+0] += p * vv.x;
          ctxa[4*j+1] += p * vv.y;
          ctxa[4*j+2] += p * vv.z;
          ctxa[4*j+3] += p * vv.w;
        }
      }
    }
  }
#pragma unroll
  for (int e = 0; e < 32; ++e) csh[(tg * 32 + q) * 33 + e] = ctxa[e];
  __syncthreads();
  {
    int qq = tid >> 3, e4 = (tid & 7) << 2;
    float4 o = make_float4(0.f, 0.f, 0.f, 0.f);
#pragma unroll
    for (int g = 0; g < 8; ++g) {
      const float* cp = &csh[(g * 32 + qq) * 33 + e4];
      o.x += cp[0]; o.y += cp[1]; o.z += cp[2]; o.w += cp[3];
    }
    *(float4*)(ctxb + ((size_t)(b * SEQ + q0 + qq)) * EMB + h * HD + e4) = o;
  }
}

// ---------------------------------------------------------------------------
extern "C" void kernel_launch(void* const* d_in, const int* in_sizes, int n_in,
                              void* d_out, int out_size, void* d_ws, size_t ws_size,
                              hipStream_t stream)
{
  const float* x  = (const float*)d_in[0];
  const float* Wq = (const float*)d_in[1];
  const float* bq = (const float*)d_in[2];
  const float* Wk = (const float*)d_in[3];
  const float* bk = (const float*)d_in[4];
  const float* Wv = (const float*)d_in[5];
  const float* bv = (const float*)d_in[6];
  const float* Wo = (const float*)d_in[7];
  const float* bo = (const float*)d_in[8];

  float* out  = (float*)d_out;
  float* attn = out + (size_t)NB * SEQ * EMB;   // [B,S,S] region of d_out

  float* qbuf = (float*)d_ws;
  float* kbuf = qbuf + (size_t)NB * SEQ * EMB;
  float* vbuf = kbuf + (size_t)NB * SEQ * EMB;
  float* ctxb = vbuf + (size_t)NB * SEQ * EMB;
  float* den  = ctxb + (size_t)NB * SEQ * EMB;          // B*H*S floats
  ull*  maskw = (ull*)(den + (size_t)NB * NH * SEQ);    // B*S*32 words

  const dim3 blk(256);
  const long strideXB = (long)SEQ * EMB;
  const long strideSB = (long)SEQ * SEQ;

  // Q/K/V projections: [8192,256] = x @ W^T + b
  gemm_abT<<<dim3(128, 4, 1), blk, 0, stream>>>(x, Wq, bq, qbuf, EMB, EMB, EMB, 0, 0, 0, 1.f);
  gemm_abT<<<dim3(128, 4, 1), blk, 0, stream>>>(x, Wk, bk, kbuf, EMB, EMB, EMB, 0, 0, 0, 1.f);
  gemm_abT<<<dim3(128, 4, 1), blk, 0, stream>>>(x, Wv, bv, vbuf, EMB, EMB, EMB, 0, 0, 0, 1.f);

  // scores = x @ x^T / 16, written into the attn_weights region of d_out
  gemm_abT<<<dim3(32, 32, NB), blk, 0, stream>>>(x, x, nullptr, attn,
      EMB, EMB, SEQ, strideXB, strideXB, strideSB, 0.0625f);

  // top-k mask bits per row
  topk_mask<<<dim3(NB * SEQ), blk, 0, stream>>>(attn, maskw);

  // reset attn region to zero (probs accumulate into it)
  zero_attn<<<dim3((NB * SEQ * SEQ / 4 + 255) / 256), blk, 0, stream>>>(
      (float4*)attn, NB * SEQ * SEQ / 4);

  // softmax denominators, then probs/ctx
  attn_den<<<dim3(SEQ / 32, NH, NB), blk, 0, stream>>>(qbuf, kbuf, maskw, den);
  attn_ctx<<<dim3(SEQ / 32, NH, NB), blk, 0, stream>>>(qbuf, kbuf, vbuf, maskw, den, attn, ctxb);

  // out = ctx @ Wo^T + bo
  gemm_abT<<<dim3(128, 4, 1), blk, 0, stream>>>(ctxb, Wo, bo, out, EMB, EMB, EMB, 0, 0, 0, 1.f);
}

// Round 2
// 656.195 us; speedup vs baseline: 1.8601x; 1.8601x over previous
//
#include <hip/hip_runtime.h>

#define SEQ  2048
#define EMB  256
#define NH   8
#define HD   32
#define NB   4
#define KTOP 204
#define IDXP 208   // padded row stride for index list

typedef unsigned long long ull;
typedef unsigned short u16;

__device__ __forceinline__ unsigned f2ord(float f) {
  unsigned u = __float_as_uint(f);
  return (u & 0x80000000u) ? ~u : (u | 0x80000000u);
}

// ---------------------------------------------------------------------------
// Generic fp32 GEMM: C[m,n] = scale * sum_k A[m,k]*B[n,k] + bias[n]
// 64x64 C tile per 256-thread block, 4x4 per thread, K=EMB=256 fixed.
// ---------------------------------------------------------------------------
__global__ __launch_bounds__(256) void gemm_abT(
    const float* __restrict__ A, const float* __restrict__ B,
    const float* __restrict__ bias, float* __restrict__ C,
    int lda, int ldb, int ldc,
    long bsA, long bsB, long bsC, float scale)
{
  __shared__ float As[16][68];
  __shared__ float Bs[16][68];
  const int tid = threadIdx.x;
  const int m0 = blockIdx.x * 64, n0 = blockIdx.y * 64;
  const float* Ab = A + (size_t)blockIdx.z * bsA;
  const float* Bb = B + (size_t)blockIdx.z * bsB;
  float* Cb = C + (size_t)blockIdx.z * bsC;
  const int lm = tid >> 2;          // 0..63
  const int lk = (tid & 3) << 2;    // 0,4,8,12
  const int mt = tid >> 4;          // 0..15
  const int nt = tid & 15;          // 0..15
  float acc[4][4] = {{0.f}};
  for (int k0 = 0; k0 < EMB; k0 += 16) {
    float4 av = *(const float4*)(Ab + (size_t)(m0 + lm) * lda + k0 + lk);
    float4 bv = *(const float4*)(Bb + (size_t)(n0 + lm) * ldb + k0 + lk);
    __syncthreads();
    As[lk+0][lm] = av.x; As[lk+1][lm] = av.y; As[lk+2][lm] = av.z; As[lk+3][lm] = av.w;
    Bs[lk+0][lm] = bv.x; Bs[lk+1][lm] = bv.y; Bs[lk+2][lm] = bv.z; Bs[lk+3][lm] = bv.w;
    __syncthreads();
#pragma unroll
    for (int kk = 0; kk < 16; ++kk) {
      float4 a4 = *(const float4*)&As[kk][mt << 2];
      float4 b4 = *(const float4*)&Bs[kk][nt << 2];
      acc[0][0] += a4.x*b4.x; acc[0][1] += a4.x*b4.y; acc[0][2] += a4.x*b4.z; acc[0][3] += a4.x*b4.w;
      acc[1][0] += a4.y*b4.x; acc[1][1] += a4.y*b4.y; acc[1][2] += a4.y*b4.z; acc[1][3] += a4.y*b4.w;
      acc[2][0] += a4.z*b4.x; acc[2][1] += a4.z*b4.y; acc[2][2] += a4.z*b4.z; acc[2][3] += a4.z*b4.w;
      acc[3][0] += a4.w*b4.x; acc[3][1] += a4.w*b4.y; acc[3][2] += a4.w*b4.z; acc[3][3] += a4.w*b4.w;
    }
  }
  float4 bi = make_float4(0.f, 0.f, 0.f, 0.f);
  if (bias) bi = *(const float4*)(bias + n0 + (nt << 2));
#pragma unroll
  for (int r = 0; r < 4; ++r) {
    float4 o;
    o.x = acc[r][0]*scale + bi.x;
    o.y = acc[r][1]*scale + bi.y;
    o.z = acc[r][2]*scale + bi.z;
    o.w = acc[r][3]*scale + bi.w;
    *(float4*)(Cb + (size_t)(m0 + (mt << 2) + r) * ldc + n0 + (nt << 2)) = o;
  }
}

// ---------------------------------------------------------------------------
// Top-k=204 per row of scores [8192 rows x 2048]. One block per row.
// Binary search k-th largest on ordinal-mapped bits; ties resolved in
// ascending index order (matches lax.top_k / stable argsort semantics).
// Emits a compacted ASCENDING index list: exactly KTOP u16 per row.
// ---------------------------------------------------------------------------
__global__ __launch_bounds__(256) void topk_idx(
    const float* __restrict__ scores, u16* __restrict__ idxl)
{
  const int r = blockIdx.x;
  const int tid = threadIdx.x;
  const float* row = scores + (size_t)r * SEQ;
  unsigned key[8];
  {
    float4 f0 = *(const float4*)(row + tid * 8);
    float4 f1 = *(const float4*)(row + tid * 8 + 4);
    key[0]=f2ord(f0.x); key[1]=f2ord(f0.y); key[2]=f2ord(f0.z); key[3]=f2ord(f0.w);
    key[4]=f2ord(f1.x); key[5]=f2ord(f1.y); key[6]=f2ord(f1.z); key[7]=f2ord(f1.w);
  }
  __shared__ int wsum[4];
  __shared__ int total_sh;
  __shared__ int scan_sh[256];
  const int lane = tid & 63, wid = tid >> 6;

  unsigned lo = 0u, hi = 0xFFFFFFFFu;
  while (lo < hi) {
    unsigned mid = (unsigned)((((ull)lo + (ull)hi) + 1ull) >> 1);
    int c = 0;
#pragma unroll
    for (int j = 0; j < 8; ++j) c += (key[j] >= mid) ? 1 : 0;
    for (int off = 32; off > 0; off >>= 1) c += __shfl_down(c, off, 64);
    if (lane == 0) wsum[wid] = c;
    __syncthreads();
    if (tid == 0) total_sh = wsum[0] + wsum[1] + wsum[2] + wsum[3];
    __syncthreads();
    int cnt = total_sh;
    __syncthreads();
    if (cnt >= KTOP) lo = mid; else hi = mid - 1;
  }
  const unsigned V = lo;

  int cgt = 0, ceq = 0;
#pragma unroll
  for (int j = 0; j < 8; ++j) {
    cgt += (key[j] > V) ? 1 : 0;
    ceq += (key[j] == V) ? 1 : 0;
  }
  int cg = cgt;
  for (int off = 32; off > 0; off >>= 1) cg += __shfl_down(cg, off, 64);
  if (lane == 0) wsum[wid] = cg;
  __syncthreads();
  if (tid == 0) total_sh = wsum[0] + wsum[1] + wsum[2] + wsum[3];
  __syncthreads();
  const int MEQ = KTOP - total_sh;   // >=1 equals to take, lowest index first

  // inclusive scan of per-thread equal counts
  scan_sh[tid] = ceq;
  __syncthreads();
  for (int off = 1; off < 256; off <<= 1) {
    int v = (tid >= off) ? scan_sh[tid - off] : 0;
    __syncthreads();
    scan_sh[tid] += v;
    __syncthreads();
  }
  int run = scan_sh[tid] - ceq;      // equals strictly before my chunk

  unsigned bits = 0;
#pragma unroll
  for (int j = 0; j < 8; ++j) {
    bool e = (key[j] == V);
    bool sel = (key[j] > V) || (e && (run < MEQ));
    if (e) run++;
    if (sel) bits |= (1u << j);
  }
  int csel = __popc(bits);

  // inclusive scan of selected counts -> write positions
  __syncthreads();
  scan_sh[tid] = csel;
  __syncthreads();
  for (int off = 1; off < 256; off <<= 1) {
    int v = (tid >= off) ? scan_sh[tid - off] : 0;
    __syncthreads();
    scan_sh[tid] += v;
    __syncthreads();
  }
  int base = scan_sh[tid] - csel;
  u16* orow = idxl + (size_t)r * IDXP;
#pragma unroll
  for (int j = 0; j < 8; ++j) {
    if ((bits >> j) & 1u) orow[base++] = (u16)(tid * 8 + j);
  }
}

// ---------------------------------------------------------------------------
// Single-pass sparse attention. One block per (q,b). All 8 heads in-block
// (mask is head-independent). Exactly KTOP keys per query -> no divergence.
//   phase 2: logits+exp for 8 heads x 204 keys (thread = (jj,cc)=(key,head))
//   phase 3: per-head denominators (shuffle reduce)
//   phase 4: probs; attn row = head-mean, written directly (row zeroed first)
//   phase 5: ctx[h*32+d] = sum_j p[h][j] * V[idx[j]][h*32+d]
// ---------------------------------------------------------------------------
__global__ __launch_bounds__(256) void sparse_attn(
    const float* __restrict__ qb, const float* __restrict__ kb,
    const float* __restrict__ vb, const u16* __restrict__ idxl,
    float* __restrict__ attn, float* __restrict__ ctxb)
{
  const int q = blockIdx.x, b = blockIdx.y;
  const int tid = threadIdx.x;
  __shared__ int   ish[IDXP];
  __shared__ float esh[8 * IDXP];
  __shared__ float idsh[8];

  const int row = b * SEQ + q;
  if (tid < KTOP) ish[tid] = (int)idxl[(size_t)row * IDXP + tid];

  // zero my attn row (this block owns it entirely; scatter comes after barrier)
  float* arow = attn + (size_t)row * SEQ;
  float4 z4 = make_float4(0.f, 0.f, 0.f, 0.f);
  *(float4*)(arow + tid * 8)     = z4;
  *(float4*)(arow + tid * 8 + 4) = z4;

  // Q slice for my head in registers
  const int jj = tid >> 3, cc = tid & 7;
  const float* qrow = qb + (size_t)row * EMB + cc * HD;
  float4 qv[8];
#pragma unroll
  for (int u = 0; u < 8; ++u) qv[u] = *(const float4*)(qrow + 4 * u);

  __syncthreads();   // ish visible

  const float scale = 0.17677669529663687f;  // 1/sqrt(32)
  const float* kbase = kb + (size_t)(b * SEQ) * EMB + cc * HD;
#pragma unroll
  for (int it = 0; it < 7; ++it) {
    int j = jj + 32 * it;
    if (j < KTOP) {
      const float* kr = kbase + (size_t)ish[j] * EMB;
      float s = 0.f;
#pragma unroll
      for (int u = 0; u < 8; ++u) {
        float4 kv = *(const float4*)(kr + 4 * u);
        s += qv[u].x*kv.x + qv[u].y*kv.y + qv[u].z*kv.z + qv[u].w*kv.w;
      }
      esh[cc * IDXP + j] = __expf(s * scale);
    }
  }
  __syncthreads();

  // per-head softmax denominator
  {
    int h = tid >> 5, l = tid & 31;
    float s = 0.f;
    for (int j = l; j < KTOP; j += 32) s += esh[h * IDXP + j];
#pragma unroll
    for (int off = 16; off > 0; off >>= 1) s += __shfl_down(s, off, 32);
    if (l == 0) idsh[h] = 1.0f / s;
  }
  __syncthreads();

  // probs in-place; head-mean scatter into attn row
  if (tid < KTOP) {
    float ps = 0.f;
#pragma unroll
    for (int h = 0; h < 8; ++h) {
      float p = esh[h * IDXP + tid] * idsh[h];
      esh[h * IDXP + tid] = p;
      ps += p;
    }
    arow[ish[tid]] = ps * 0.125f;
  }
  __syncthreads();

  // ctx gather: thread (h,d)
  {
    int h = tid >> 5, d = tid & 31;
    const float* vbb = vb + (size_t)(b * SEQ) * EMB + h * HD + d;
    const float* ps  = &esh[h * IDXP];
    float acc = 0.f;
#pragma unroll 4
    for (int j = 0; j < KTOP; ++j)
      acc += ps[j] * vbb[(size_t)ish[j] * EMB];
    ctxb[(size_t)row * EMB + h * HD + d] = acc;
  }
}

// ---------------------------------------------------------------------------
extern "C" void kernel_launch(void* const* d_in, const int* in_sizes, int n_in,
                              void* d_out, int out_size, void* d_ws, size_t ws_size,
                              hipStream_t stream)
{
  const float* x  = (const float*)d_in[0];
  const float* Wq = (const float*)d_in[1];
  const float* bq = (const float*)d_in[2];
  const float* Wk = (const float*)d_in[3];
  const float* bk = (const float*)d_in[4];
  const float* Wv = (const float*)d_in[5];
  const float* bv = (const float*)d_in[6];
  const float* Wo = (const float*)d_in[7];
  const float* bo = (const float*)d_in[8];

  float* out  = (float*)d_out;
  float* attn = out + (size_t)NB * SEQ * EMB;   // [B,S,S] region of d_out

  float* qbuf = (float*)d_ws;
  float* kbuf = qbuf + (size_t)NB * SEQ * EMB;
  float* vbuf = kbuf + (size_t)NB * SEQ * EMB;
  float* ctxb = vbuf + (size_t)NB * SEQ * EMB;
  u16*  idxl  = (u16*)(ctxb + (size_t)NB * SEQ * EMB);  // B*S*IDXP u16

  const dim3 blk(256);
  const long strideXB = (long)SEQ * EMB;
  const long strideSB = (long)SEQ * SEQ;

  // Q/K/V projections: [8192,256] = x @ W^T + b
  gemm_abT<<<dim3(128, 4, 1), blk, 0, stream>>>(x, Wq, bq, qbuf, EMB, EMB, EMB, 0, 0, 0, 1.f);
  gemm_abT<<<dim3(128, 4, 1), blk, 0, stream>>>(x, Wk, bk, kbuf, EMB, EMB, EMB, 0, 0, 0, 1.f);
  gemm_abT<<<dim3(128, 4, 1), blk, 0, stream>>>(x, Wv, bv, vbuf, EMB, EMB, EMB, 0, 0, 0, 1.f);

  // scores = x @ x^T / 16, written into the attn_weights region of d_out
  gemm_abT<<<dim3(32, 32, NB), blk, 0, stream>>>(x, x, nullptr, attn,
      EMB, EMB, SEQ, strideXB, strideXB, strideSB, 0.0625f);

  // compacted top-k index lists (ascending per row)
  topk_idx<<<dim3(NB * SEQ), blk, 0, stream>>>(attn, idxl);

  // fused sparse attention: zero+scatter attn rows, ctx
  sparse_attn<<<dim3(SEQ, NB), blk, 0, stream>>>(qbuf, kbuf, vbuf, idxl, attn, ctxb);

  // out = ctx @ Wo^T + bo
  gemm_abT<<<dim3(128, 4, 1), blk, 0, stream>>>(ctxb, Wo, bo, out, EMB, EMB, EMB, 0, 0, 0, 1.f);
}

// Round 3
// 517.565 us; speedup vs baseline: 2.3583x; 1.2679x over previous
//
#include <hip/hip_runtime.h>

#define SEQ  2048
#define EMB  256
#define NH   8
#define HD   32
#define NB   4
#define KTOP 204
#define IDXP 208   // padded row stride for index list
#define JPW  51    // keys per wave in sparse_attn (4*51 = 204)

typedef unsigned long long ull;
typedef unsigned short u16;

__device__ __forceinline__ unsigned f2ord(float f) {
  unsigned u = __float_as_uint(f);
  return (u & 0x80000000u) ? ~u : (u | 0x80000000u);
}

// ---------------------------------------------------------------------------
// fp32 GEMM, 64x64 tile, 4x4/thread: C[m,n] = scale*sum_k A[m,k]B[n,k] + bias
// Used for the small E x E projections (QKV, out).
// ---------------------------------------------------------------------------
__global__ __launch_bounds__(256) void gemm_abT(
    const float* __restrict__ A, const float* __restrict__ B,
    const float* __restrict__ bias, float* __restrict__ C,
    int lda, int ldb, int ldc,
    long bsA, long bsB, long bsC, float scale)
{
  __shared__ float As[16][68];
  __shared__ float Bs[16][68];
  const int tid = threadIdx.x;
  const int m0 = blockIdx.x * 64, n0 = blockIdx.y * 64;
  const float* Ab = A + (size_t)blockIdx.z * bsA;
  const float* Bb = B + (size_t)blockIdx.z * bsB;
  float* Cb = C + (size_t)blockIdx.z * bsC;
  const int lm = tid >> 2;
  const int lk = (tid & 3) << 2;
  const int mt = tid >> 4;
  const int nt = tid & 15;
  float acc[4][4] = {{0.f}};
  for (int k0 = 0; k0 < EMB; k0 += 16) {
    float4 av = *(const float4*)(Ab + (size_t)(m0 + lm) * lda + k0 + lk);
    float4 bv = *(const float4*)(Bb + (size_t)(n0 + lm) * ldb + k0 + lk);
    __syncthreads();
    As[lk+0][lm] = av.x; As[lk+1][lm] = av.y; As[lk+2][lm] = av.z; As[lk+3][lm] = av.w;
    Bs[lk+0][lm] = bv.x; Bs[lk+1][lm] = bv.y; Bs[lk+2][lm] = bv.z; Bs[lk+3][lm] = bv.w;
    __syncthreads();
#pragma unroll
    for (int kk = 0; kk < 16; ++kk) {
      float4 a4 = *(const float4*)&As[kk][mt << 2];
      float4 b4 = *(const float4*)&Bs[kk][nt << 2];
      acc[0][0] += a4.x*b4.x; acc[0][1] += a4.x*b4.y; acc[0][2] += a4.x*b4.z; acc[0][3] += a4.x*b4.w;
      acc[1][0] += a4.y*b4.x; acc[1][1] += a4.y*b4.y; acc[1][2] += a4.y*b4.z; acc[1][3] += a4.y*b4.w;
      acc[2][0] += a4.z*b4.x; acc[2][1] += a4.z*b4.y; acc[2][2] += a4.z*b4.z; acc[2][3] += a4.z*b4.w;
      acc[3][0] += a4.w*b4.x; acc[3][1] += a4.w*b4.y; acc[3][2] += a4.w*b4.z; acc[3][3] += a4.w*b4.w;
    }
  }
  float4 bi = make_float4(0.f, 0.f, 0.f, 0.f);
  if (bias) bi = *(const float4*)(bias + n0 + (nt << 2));
#pragma unroll
  for (int r = 0; r < 4; ++r) {
    float4 o;
    o.x = acc[r][0]*scale + bi.x;
    o.y = acc[r][1]*scale + bi.y;
    o.z = acc[r][2]*scale + bi.z;
    o.w = acc[r][3]*scale + bi.w;
    *(float4*)(Cb + (size_t)(m0 + (mt << 2) + r) * ldc + n0 + (nt << 2)) = o;
  }
}

// ---------------------------------------------------------------------------
// fp32 GEMM, 128x128 tile, 8x8/thread — for the big scores GEMM (x @ x^T).
// VALU-bound: 64 FMA per 4 ds_read_b128.
// ---------------------------------------------------------------------------
__global__ __launch_bounds__(256) void gemm128_abT(
    const float* __restrict__ A, const float* __restrict__ B,
    float* __restrict__ C, int ldc,
    long bsA, long bsB, long bsC, float scale)
{
  __shared__ float As[16][132];
  __shared__ float Bs[16][132];
  const int tid = threadIdx.x;
  const int m0 = blockIdx.x * 128, n0 = blockIdx.y * 128;
  const float* Ab = A + (size_t)blockIdx.z * bsA;
  const float* Bb = B + (size_t)blockIdx.z * bsB;
  float* Cb = C + (size_t)blockIdx.z * bsC;
  const int lm = tid >> 1;          // 0..127
  const int lk = (tid & 1) << 3;    // 0 or 8
  const int mt = tid >> 4;          // 0..15
  const int nt = tid & 15;          // 0..15
  float acc[8][8] = {{0.f}};
  for (int k0 = 0; k0 < EMB; k0 += 16) {
    float4 a0 = *(const float4*)(Ab + (size_t)(m0 + lm) * EMB + k0 + lk);
    float4 a1 = *(const float4*)(Ab + (size_t)(m0 + lm) * EMB + k0 + lk + 4);
    float4 b0 = *(const float4*)(Bb + (size_t)(n0 + lm) * EMB + k0 + lk);
    float4 b1 = *(const float4*)(Bb + (size_t)(n0 + lm) * EMB + k0 + lk + 4);
    __syncthreads();
    As[lk+0][lm]=a0.x; As[lk+1][lm]=a0.y; As[lk+2][lm]=a0.z; As[lk+3][lm]=a0.w;
    As[lk+4][lm]=a1.x; As[lk+5][lm]=a1.y; As[lk+6][lm]=a1.z; As[lk+7][lm]=a1.w;
    Bs[lk+0][lm]=b0.x; Bs[lk+1][lm]=b0.y; Bs[lk+2][lm]=b0.z; Bs[lk+3][lm]=b0.w;
    Bs[lk+4][lm]=b1.x; Bs[lk+5][lm]=b1.y; Bs[lk+6][lm]=b1.z; Bs[lk+7][lm]=b1.w;
    __syncthreads();
#pragma unroll
    for (int kk = 0; kk < 16; ++kk) {
      float4 aA = *(const float4*)&As[kk][mt * 8];
      float4 aB = *(const float4*)&As[kk][mt * 8 + 4];
      float4 bA = *(const float4*)&Bs[kk][nt * 8];
      float4 bB = *(const float4*)&Bs[kk][nt * 8 + 4];
      float am[8] = {aA.x,aA.y,aA.z,aA.w,aB.x,aB.y,aB.z,aB.w};
      float bn[8] = {bA.x,bA.y,bA.z,bA.w,bB.x,bB.y,bB.z,bB.w};
#pragma unroll
      for (int i = 0; i < 8; ++i)
#pragma unroll
        for (int j = 0; j < 8; ++j)
          acc[i][j] += am[i] * bn[j];
    }
  }
#pragma unroll
  for (int r = 0; r < 8; ++r) {
    float4 o0, o1;
    o0.x = acc[r][0]*scale; o0.y = acc[r][1]*scale; o0.z = acc[r][2]*scale; o0.w = acc[r][3]*scale;
    o1.x = acc[r][4]*scale; o1.y = acc[r][5]*scale; o1.z = acc[r][6]*scale; o1.w = acc[r][7]*scale;
    float* cp = Cb + (size_t)(m0 + mt * 8 + r) * ldc + n0 + nt * 8;
    *(float4*)cp = o0;
    *(float4*)(cp + 4) = o1;
  }
}

// ---------------------------------------------------------------------------
// Top-k=204 per row of scores [8192 rows x 2048]. One block per row.
// Binary search k-th largest on ordinal-mapped bits; ties resolved in
// ascending index order. Emits compacted ASCENDING index list (KTOP u16/row).
// ---------------------------------------------------------------------------
__global__ __launch_bounds__(256) void topk_idx(
    const float* __restrict__ scores, u16* __restrict__ idxl)
{
  const int r = blockIdx.x;
  const int tid = threadIdx.x;
  const float* row = scores + (size_t)r * SEQ;
  unsigned key[8];
  {
    float4 f0 = *(const float4*)(row + tid * 8);
    float4 f1 = *(const float4*)(row + tid * 8 + 4);
    key[0]=f2ord(f0.x); key[1]=f2ord(f0.y); key[2]=f2ord(f0.z); key[3]=f2ord(f0.w);
    key[4]=f2ord(f1.x); key[5]=f2ord(f1.y); key[6]=f2ord(f1.z); key[7]=f2ord(f1.w);
  }
  __shared__ int wsum[4];
  __shared__ int total_sh;
  __shared__ int scan_sh[256];
  const int lane = tid & 63, wid = tid >> 6;

  unsigned lo = 0u, hi = 0xFFFFFFFFu;
  while (lo < hi) {
    unsigned mid = (unsigned)((((ull)lo + (ull)hi) + 1ull) >> 1);
    int c = 0;
#pragma unroll
    for (int j = 0; j < 8; ++j) c += (key[j] >= mid) ? 1 : 0;
    for (int off = 32; off > 0; off >>= 1) c += __shfl_down(c, off, 64);
    if (lane == 0) wsum[wid] = c;
    __syncthreads();
    if (tid == 0) total_sh = wsum[0] + wsum[1] + wsum[2] + wsum[3];
    __syncthreads();
    int cnt = total_sh;
    __syncthreads();
    if (cnt >= KTOP) lo = mid; else hi = mid - 1;
  }
  const unsigned V = lo;

  int cgt = 0, ceq = 0;
#pragma unroll
  for (int j = 0; j < 8; ++j) {
    cgt += (key[j] > V) ? 1 : 0;
    ceq += (key[j] == V) ? 1 : 0;
  }
  int cg = cgt;
  for (int off = 32; off > 0; off >>= 1) cg += __shfl_down(cg, off, 64);
  if (lane == 0) wsum[wid] = cg;
  __syncthreads();
  if (tid == 0) total_sh = wsum[0] + wsum[1] + wsum[2] + wsum[3];
  __syncthreads();
  const int MEQ = KTOP - total_sh;

  scan_sh[tid] = ceq;
  __syncthreads();
  for (int off = 1; off < 256; off <<= 1) {
    int v = (tid >= off) ? scan_sh[tid - off] : 0;
    __syncthreads();
    scan_sh[tid] += v;
    __syncthreads();
  }
  int run = scan_sh[tid] - ceq;

  unsigned bits = 0;
#pragma unroll
  for (int j = 0; j < 8; ++j) {
    bool e = (key[j] == V);
    bool sel = (key[j] > V) || (e && (run < MEQ));
    if (e) run++;
    if (sel) bits |= (1u << j);
  }
  int csel = __popc(bits);

  __syncthreads();
  scan_sh[tid] = csel;
  __syncthreads();
  for (int off = 1; off < 256; off <<= 1) {
    int v = (tid >= off) ? scan_sh[tid - off] : 0;
    __syncthreads();
    scan_sh[tid] += v;
    __syncthreads();
  }
  int base = scan_sh[tid] - csel;
  u16* orow = idxl + (size_t)r * IDXP;
#pragma unroll
  for (int j = 0; j < 8; ++j) {
    if ((bits >> j) & 1u) orow[base++] = (u16)(tid * 8 + j);
  }
}

// ---------------------------------------------------------------------------
// Single-pass sparse attention, v2 (coalesced row gathers).
// One block per (q,b). Lane l of each wave owns dims l*4..l*4+3 (head l>>3);
// each of the 4 waves owns 51 of the 204 selected keys.
//   QK: one coalesced 1KB K-row load per wave per key; 8-lane shuffle dot.
//   probs in LDS transposed [j][h] stride 9 (conflict-free).
//   ctx: coalesced 1KB V-row loads, 4-way LDS reduction.
// ---------------------------------------------------------------------------
__global__ __launch_bounds__(256) void sparse_attn(
    const float* __restrict__ qb, const float* __restrict__ kb,
    const float* __restrict__ vb, const u16* __restrict__ idxl,
    float* __restrict__ attn, float* __restrict__ ctxb)
{
  const int q = blockIdx.x, b = blockIdx.y;
  const int tid = threadIdx.x;
  const int wv = tid >> 6, ln = tid & 63;
  const int h = ln >> 3, hd8 = ln & 7;
  __shared__ int   ish[IDXP];
  __shared__ float psh[KTOP * 9 + 4];   // [j][h], stride 9
  __shared__ float idsh[NH];
  __shared__ float csh[4][EMB + 8];

  const int row = b * SEQ + q;
  if (tid < KTOP) ish[tid] = (int)idxl[(size_t)row * IDXP + tid];

  // zero my attn row (block owns it; scatter after barriers)
  float* arow = attn + (size_t)row * SEQ;
  float4 z4 = make_float4(0.f, 0.f, 0.f, 0.f);
  *(float4*)(arow + tid * 8)     = z4;
  *(float4*)(arow + tid * 8 + 4) = z4;

  // q fragment: lane ln holds q[row][ln*4 .. ln*4+3]
  float4 qv = *(const float4*)(qb + (size_t)row * EMB + ln * 4);

  __syncthreads();

  const float scale = 0.17677669529663687f;  // 1/sqrt(32)
  const float* kbB = kb + (size_t)(b * SEQ) * EMB;
#pragma unroll 3
  for (int t = 0; t < JPW; ++t) {
    int j = wv * JPW + t;
    const float4 kv = *(const float4*)(kbB + (size_t)ish[j] * EMB + ln * 4);
    float p = qv.x*kv.x + qv.y*kv.y + qv.z*kv.z + qv.w*kv.w;
    p += __shfl_xor(p, 4, 64);
    p += __shfl_xor(p, 2, 64);
    p += __shfl_xor(p, 1, 64);
    if (hd8 == 0) psh[j * 9 + h] = __expf(p * scale);
  }
  __syncthreads();

  // per-head denominators: 8 groups of 32 lanes
  {
    int h2 = tid >> 5, l = tid & 31;
    float s = 0.f;
    for (int j = l; j < KTOP; j += 32) s += psh[j * 9 + h2];
#pragma unroll
    for (int off = 16; off > 0; off >>= 1) s += __shfl_down(s, off, 32);
    if (l == 0) idsh[h2] = 1.0f / s;
  }
  __syncthreads();

  // normalize in place; head-mean scatter into attn row
  if (tid < KTOP) {
    float ps = 0.f;
#pragma unroll
    for (int hh = 0; hh < 8; ++hh) {
      float pp = psh[tid * 9 + hh] * idsh[hh];
      psh[tid * 9 + hh] = pp;
      ps += pp;
    }
    arow[ish[tid]] = ps * 0.125f;
  }
  __syncthreads();

  // ctx: wave wv accumulates its 51 keys; lane ln covers dims ln*4..+3
  {
    const float* vbB = vb + (size_t)(b * SEQ) * EMB;
    float4 acc = z4;
#pragma unroll 3
    for (int t = 0; t < JPW; ++t) {
      int j = wv * JPW + t;
      const float4 vv = *(const float4*)(vbB + (size_t)ish[j] * EMB + ln * 4);
      float pp = psh[j * 9 + h];
      acc.x += pp*vv.x; acc.y += pp*vv.y; acc.z += pp*vv.z; acc.w += pp*vv.w;
    }
    *(float4*)&csh[wv][ln * 4] = acc;
  }
  __syncthreads();
  if (tid < 64) {
    float4 o = z4;
#pragma unroll
    for (int g = 0; g < 4; ++g) {
      float4 v = *(const float4*)&csh[g][tid * 4];
      o.x += v.x; o.y += v.y; o.z += v.z; o.w += v.w;
    }
    *(float4*)(ctxb + (size_t)row * EMB + tid * 4) = o;
  }
}

// ---------------------------------------------------------------------------
extern "C" void kernel_launch(void* const* d_in, const int* in_sizes, int n_in,
                              void* d_out, int out_size, void* d_ws, size_t ws_size,
                              hipStream_t stream)
{
  const float* x  = (const float*)d_in[0];
  const float* Wq = (const float*)d_in[1];
  const float* bq = (const float*)d_in[2];
  const float* Wk = (const float*)d_in[3];
  const float* bk = (const float*)d_in[4];
  const float* Wv = (const float*)d_in[5];
  const float* bv = (const float*)d_in[6];
  const float* Wo = (const float*)d_in[7];
  const float* bo = (const float*)d_in[8];

  float* out  = (float*)d_out;
  float* attn = out + (size_t)NB * SEQ * EMB;   // [B,S,S] region of d_out

  float* qbuf = (float*)d_ws;
  float* kbuf = qbuf + (size_t)NB * SEQ * EMB;
  float* vbuf = kbuf + (size_t)NB * SEQ * EMB;
  float* ctxb = vbuf + (size_t)NB * SEQ * EMB;
  u16*  idxl  = (u16*)(ctxb + (size_t)NB * SEQ * EMB);  // B*S*IDXP u16

  const dim3 blk(256);
  const long strideXB = (long)SEQ * EMB;
  const long strideSB = (long)SEQ * SEQ;

  // Q/K/V projections: [8192,256] = x @ W^T + b
  gemm_abT<<<dim3(128, 4, 1), blk, 0, stream>>>(x, Wq, bq, qbuf, EMB, EMB, EMB, 0, 0, 0, 1.f);
  gemm_abT<<<dim3(128, 4, 1), blk, 0, stream>>>(x, Wk, bk, kbuf, EMB, EMB, EMB, 0, 0, 0, 1.f);
  gemm_abT<<<dim3(128, 4, 1), blk, 0, stream>>>(x, Wv, bv, vbuf, EMB, EMB, EMB, 0, 0, 0, 1.f);

  // scores = x @ x^T / 16, into the attn_weights region of d_out (128-tile)
  gemm128_abT<<<dim3(16, 16, NB), blk, 0, stream>>>(x, x, attn, SEQ,
      strideXB, strideXB, strideSB, 0.0625f);

  // compacted top-k index lists (ascending per row)
  topk_idx<<<dim3(NB * SEQ), blk, 0, stream>>>(attn, idxl);

  // fused sparse attention
  sparse_attn<<<dim3(SEQ, NB), blk, 0, stream>>>(qbuf, kbuf, vbuf, idxl, attn, ctxb);

  // out = ctx @ Wo^T + bo
  gemm_abT<<<dim3(128, 4, 1), blk, 0, stream>>>(ctxb, Wo, bo, out, EMB, EMB, EMB, 0, 0, 0, 1.f);
}